// Round 1
// baseline (296.410 us; speedup 1.0000x reference)
//
#include <hip/hip_runtime.h>
#include <cmath>

#define NLVL 16
#define TSIZE (1u << 19)
#define HMASK ((1u << 19) - 1u)
#define PRIME1 2654435761u

struct ResParams { float rf[NLVL]; int ri[NLVL]; };

__global__ __launch_bounds__(256) void hash_embed(
    const float2* __restrict__ x,
    const float2* __restrict__ emb,
    float* __restrict__ out,
    ResParams rp, int n)
{
    __shared__ float2 lds[NLVL * 256];   // [level][tid], 32 KiB
    const int tid = threadIdx.x;
    const int i = blockIdx.x * 256 + tid;
    float2 xy = make_float2(0.f, 0.f);
    if (i < n) xy = x[i];

    #pragma unroll
    for (int half = 0; half < 2; ++half) {
        float2 f[32];
        float w0v[8], w1v[8];
        // phase 1: compute addresses, issue all 32 gathers of this batch
        #pragma unroll
        for (int j = 0; j < 8; ++j) {
            const int l = half * 8 + j;
            const float rf = rp.rf[l];
            const int ri = rp.ri[l];
            const float px = xy.x * rf;
            const float py = xy.y * rf;
            const float fx = floorf(px);
            const float fy = floorf(py);
            w0v[j] = px - fx;
            w1v[j] = py - fy;
            const int tx = (int)fx, ty = (int)fy;
            // reference clips corners to [0, res] inclusive; x>=0 so only upper clip
            const unsigned cx0 = (unsigned)min(tx, ri);
            const unsigned cy0 = (unsigned)min(ty, ri);
            const unsigned cx1 = (unsigned)min(tx + 1, ri);
            const unsigned cy1 = (unsigned)min(ty + 1, ri);
            const unsigned hy0 = cy0 * PRIME1;
            const unsigned hy1 = cy1 * PRIME1;
            const float2* tab = emb + (size_t)l * TSIZE;
            f[j*4+0] = tab[(cx0 ^ hy0) & HMASK];
            f[j*4+1] = tab[(cx1 ^ hy0) & HMASK];
            f[j*4+2] = tab[(cx0 ^ hy1) & HMASK];
            f[j*4+3] = tab[(cx1 ^ hy1) & HMASK];
        }
        // phase 2: bilinear blend, stash into LDS
        #pragma unroll
        for (int j = 0; j < 8; ++j) {
            const int l = half * 8 + j;
            const float w0 = w0v[j], w1 = w1v[j];
            const float u0 = 1.f - w0, u1 = 1.f - w1;
            const float2 f0 = f[j*4+0], f1 = f[j*4+1], f2 = f[j*4+2], f3 = f[j*4+3];
            const float g0 = (f0.x*u0 + f1.x*w0)*u1 + (f2.x*u0 + f3.x*w0)*w1;
            const float g1 = (f0.y*u0 + f1.y*w0)*u1 + (f2.y*u0 + f3.y*w0)*w1;
            lds[l * 256 + tid] = make_float2(g0, g1);
        }
    }
    __syncthreads();

    // coalesced write-out: block covers out[block*8192 .. +8192)
    const float* lf = (const float*)lds;  // [l][tid][c]
    const long long total = (long long)n * 32;
    const long long base = (long long)blockIdx.x * 8192;
    #pragma unroll
    for (int it = 0; it < 8; ++it) {
        const int k = (it * 256 + tid) * 4;   // float offset within block region
        if (base + k < total) {
            const int p = k >> 5;         // point within block
            const int f0i = k & 31;       // feature index (multiple of 4)
            const int l0 = f0i >> 1;      // covers levels l0, l0+1 (both feats)
            float4 v;
            v.x = lf[(l0 * 256 + p) * 2 + 0];
            v.y = lf[(l0 * 256 + p) * 2 + 1];
            v.z = lf[((l0 + 1) * 256 + p) * 2 + 0];
            v.w = lf[((l0 + 1) * 256 + p) * 2 + 1];
            *(float4*)(out + base + k) = v;
        }
    }
}

extern "C" void kernel_launch(void* const* d_in, const int* in_sizes, int n_in,
                              void* d_out, int out_size, void* d_ws, size_t ws_size,
                              hipStream_t stream) {
    const float2* x = (const float2*)d_in[0];
    const float2* emb = (const float2*)d_in[1];
    float* out = (float*)d_out;
    const int n = in_sizes[0] / 2;

    // Replicate numpy's exact double-precision chain for the per-level
    // resolutions; floor decisions at l=3,6,9,12,15 are ulp-sensitive.
    ResParams rp;
    const double b = std::exp((std::log(512.0) - std::log(16.0)) / 15.0);
    for (int l = 0; l < NLVL; ++l) {
        const double r = std::floor(16.0 * std::pow(b, (double)l));
        rp.rf[l] = (float)r;
        rp.ri[l] = (int)r;
    }

    const int grid = (n + 255) / 256;
    hash_embed<<<grid, 256, 0, stream>>>(x, emb, out, rp, n);
}